// Round 1
// baseline (1887.064 us; speedup 1.0000x reference)
//
#include <hip/hip_runtime.h>

// NGP fwd: hashgrid encode (16 levels, F=2, 2D bilinear) + MLP 32->64->64->3, fp32.
// N = 4,194,304 points. Table: [16, 2^19, 2] fp32.

constexpr unsigned TSIZE = 1u << 19;
constexpr unsigned PRIME2 = 2654435761u;

__global__ __launch_bounds__(256, 2)
void ngp_kernel(const float* __restrict__ pos,
                const float* __restrict__ table,
                const float* __restrict__ W1,   // [32,64]
                const float* __restrict__ W2,   // [64,64]
                const float* __restrict__ W3,   // [64,3]
                float* __restrict__ out,        // [N,3]
                int n)
{
    int i = blockIdx.x * blockDim.x + threadIdx.x;
    if (i >= n) return;

    float px = pos[2 * i];
    float py = pos[2 * i + 1];

    float h1[64];
#pragma unroll
    for (int j = 0; j < 64; j++) h1[j] = 0.0f;

    // ---- Encoding fused with layer 1 (feats never stored) ----
#pragma unroll
    for (int lvl = 0; lvl < 16; lvl++) {
        const unsigned res = 16u << lvl;                 // = ceil(scale)+1 exactly
        const float scale = (float)res - 1.0f;           // 16*2^lvl - 1, exact in fp32
        float pxs = fmaf(px, scale, 0.5f);
        float pys = fmaf(py, scale, 0.5f);
        float fx = floorf(pxs), fy = floorf(pys);
        float wx = pxs - fx,   wy = pys - fy;
        unsigned x0 = (unsigned)fx, y0 = (unsigned)fy;

        unsigned i00, i10, i01, i11;
        // dense iff res*res <= T  (levels 0..5: res<=512)
        if ((unsigned long long)res * (unsigned long long)res <= (unsigned long long)TSIZE) {
            i00 = x0 + y0 * res;
            i10 = i00 + 1u;
            i01 = i00 + res;
            i11 = i01 + 1u;
        } else {
            unsigned hy0 = y0 * PRIME2;
            unsigned hy1 = (y0 + 1u) * PRIME2;
            i00 = (x0 ^ hy0) & (TSIZE - 1u);
            i10 = ((x0 + 1u) ^ hy0) & (TSIZE - 1u);
            i01 = (x0 ^ hy1) & (TSIZE - 1u);
            i11 = ((x0 + 1u) ^ hy1) & (TSIZE - 1u);
        }

        const float* tl = table + (size_t)lvl * (size_t)TSIZE * 2u;
        float2 t00 = *(const float2*)(tl + 2u * i00);
        float2 t10 = *(const float2*)(tl + 2u * i10);
        float2 t01 = *(const float2*)(tl + 2u * i01);
        float2 t11 = *(const float2*)(tl + 2u * i11);

        float w00 = (1.0f - wx) * (1.0f - wy);
        float w10 = wx * (1.0f - wy);
        float w01 = (1.0f - wx) * wy;
        float w11 = wx * wy;

        float f0 = fmaf(w00, t00.x, fmaf(w10, t10.x, fmaf(w01, t01.x, w11 * t11.x)));
        float f1 = fmaf(w00, t00.y, fmaf(w10, t10.y, fmaf(w01, t01.y, w11 * t11.y)));

        const float* w1r0 = W1 + (2 * lvl) * 64;
        const float* w1r1 = W1 + (2 * lvl + 1) * 64;
#pragma unroll
        for (int j = 0; j < 64; j++) {
            h1[j] = fmaf(f0, w1r0[j], fmaf(f1, w1r1[j], h1[j]));
        }
    }

    // ReLU
#pragma unroll
    for (int j = 0; j < 64; j++) h1[j] = fmaxf(h1[j], 0.0f);

    // ---- Layer 2: 64 -> 64, ReLU ----
    float h2[64];
#pragma unroll
    for (int j = 0; j < 64; j++) h2[j] = 0.0f;
#pragma unroll
    for (int k = 0; k < 64; k++) {
        float a = h1[k];
        const float* wr = W2 + k * 64;
#pragma unroll
        for (int j = 0; j < 64; j++) {
            h2[j] = fmaf(a, wr[j], h2[j]);
        }
    }
#pragma unroll
    for (int j = 0; j < 64; j++) h2[j] = fmaxf(h2[j], 0.0f);

    // ---- Layer 3: 64 -> 3 ----
    float o0 = 0.0f, o1 = 0.0f, o2 = 0.0f;
#pragma unroll
    for (int k = 0; k < 64; k++) {
        float a = h2[k];
        o0 = fmaf(a, W3[k * 3 + 0], o0);
        o1 = fmaf(a, W3[k * 3 + 1], o1);
        o2 = fmaf(a, W3[k * 3 + 2], o2);
    }

    out[3 * i + 0] = o0;
    out[3 * i + 1] = o1;
    out[3 * i + 2] = o2;
}

extern "C" void kernel_launch(void* const* d_in, const int* in_sizes, int n_in,
                              void* d_out, int out_size, void* d_ws, size_t ws_size,
                              hipStream_t stream) {
    const float* pos   = (const float*)d_in[0];
    const float* table = (const float*)d_in[1];
    const float* W1    = (const float*)d_in[2];
    const float* W2    = (const float*)d_in[3];
    const float* W3    = (const float*)d_in[4];
    float* out = (float*)d_out;

    int n = in_sizes[0] / 2;
    int threads = 256;
    int blocks = (n + threads - 1) / threads;
    hipLaunchKernelGGL(ngp_kernel, dim3(blocks), dim3(threads), 0, stream,
                       pos, table, W1, W2, W3, out, n);
}

// Round 3
// 1366.074 us; speedup vs baseline: 1.3814x; 1.3814x over previous
//
#include <hip/hip_runtime.h>
#include <hip/hip_fp16.h>

// NGP fwd, multi-pass: per-hashed-level encode (L2-resident fp16 table) + fused MLP.
// N = 4,194,304 points. Table: [16, 2^19, 2] fp32. Levels 0-5 dense, 6-15 hashed.

constexpr unsigned TSIZE  = 1u << 19;
constexpr unsigned PRIME2 = 2654435761u;
constexpr int N_HASHED    = 10;      // levels 6..15
constexpr int LVL0_HASH   = 6;

// ---------- K0: convert hashed-level tables fp32 -> fp16 (into ws) ----------
__global__ __launch_bounds__(256)
void cvt_table(const float* __restrict__ src,     // table + 6*T*2 floats
               unsigned* __restrict__ dst,        // 10*T half2 (as u32)
               int n2)                             // pairs of entries
{
    int t = blockIdx.x * blockDim.x + threadIdx.x;
    if (t >= n2) return;
    float4 v = ((const float4*)src)[t];
    __half2 a = __floats2half2_rn(v.x, v.y);
    __half2 b = __floats2half2_rn(v.z, v.w);
    uint2 pk;
    pk.x = *(unsigned*)&a;
    pk.y = *(unsigned*)&b;
    ((uint2*)dst)[t] = pk;
}

// ---------- K1: one hashed level -> fp16 feats (level-major) ----------
__device__ __forceinline__ void hash_feat(float px, float py, float scale,
                                          const __half2* __restrict__ tbl,
                                          unsigned& out_h2)
{
    float pxs = fmaf(px, scale, 0.5f);
    float pys = fmaf(py, scale, 0.5f);
    float fx = floorf(pxs), fy = floorf(pys);
    float wx = pxs - fx,   wy = pys - fy;
    unsigned x0 = (unsigned)fx, y0 = (unsigned)fy;

    unsigned hy0 = y0 * PRIME2;
    unsigned hy1 = (y0 + 1u) * PRIME2;
    unsigned i00 = (x0 ^ hy0) & (TSIZE - 1u);
    unsigned i10 = ((x0 + 1u) ^ hy0) & (TSIZE - 1u);
    unsigned i01 = (x0 ^ hy1) & (TSIZE - 1u);
    unsigned i11 = ((x0 + 1u) ^ hy1) & (TSIZE - 1u);

    __half2 t00 = tbl[i00];
    __half2 t10 = tbl[i10];
    __half2 t01 = tbl[i01];
    __half2 t11 = tbl[i11];

    float w00 = (1.0f - wx) * (1.0f - wy);
    float w10 = wx * (1.0f - wy);
    float w01 = (1.0f - wx) * wy;
    float w11 = wx * wy;

    float f0 = w00 * __low2float(t00)  + w10 * __low2float(t10)
             + w01 * __low2float(t01)  + w11 * __low2float(t11);
    float f1 = w00 * __high2float(t00) + w10 * __high2float(t10)
             + w01 * __high2float(t01) + w11 * __high2float(t11);

    __half2 r = __floats2half2_rn(f0, f1);
    out_h2 = *(unsigned*)&r;
}

__global__ __launch_bounds__(256)
void encode_level(const float* __restrict__ pos,
                  const __half2* __restrict__ tbl,   // this level's fp16 table (2 MB)
                  uint2* __restrict__ feat,          // this level's feat slice, pair-packed
                  int nhalf, unsigned res)
{
    int t = blockIdx.x * blockDim.x + threadIdx.x;
    if (t >= nhalf) return;
    float4 p = ((const float4*)pos)[t];  // 2 points
    float scale = (float)res - 1.0f;

    uint2 pk;
    hash_feat(p.x, p.y, scale, tbl, pk.x);
    hash_feat(p.z, p.w, scale, tbl, pk.y);
    feat[t] = pk;
}

// ---------- K2: coarse dense levels + MLP ----------
__global__ __launch_bounds__(256, 2)
void mlp_kernel(const float* __restrict__ pos,
                const float* __restrict__ table,    // original fp32 table (coarse levels)
                const __half2* __restrict__ feats,  // [10][N] half2, level-major
                const float* __restrict__ W1,       // [32,64]
                const float* __restrict__ W2,       // [64,64]
                const float* __restrict__ W3,       // [64,3]
                float* __restrict__ out, int n)
{
    int i = blockIdx.x * blockDim.x + threadIdx.x;
    if (i >= n) return;

    float px = pos[2 * i];
    float py = pos[2 * i + 1];

    float h1[64];
#pragma unroll
    for (int j = 0; j < 64; j++) h1[j] = 0.0f;

    // coarse dense levels 0..5 from fp32 table (2.8 MB hot set -> cache-resident)
#pragma unroll
    for (int lvl = 0; lvl < 6; lvl++) {
        const unsigned res = 16u << lvl;
        const float scale = (float)res - 1.0f;
        float pxs = fmaf(px, scale, 0.5f);
        float pys = fmaf(py, scale, 0.5f);
        float fx = floorf(pxs), fy = floorf(pys);
        float wx = pxs - fx,   wy = pys - fy;
        unsigned x0 = (unsigned)fx, y0 = (unsigned)fy;

        unsigned i00 = x0 + y0 * res;
        unsigned i10 = i00 + 1u;
        unsigned i01 = i00 + res;
        unsigned i11 = i01 + 1u;

        const float* tl = table + (size_t)lvl * (size_t)TSIZE * 2u;
        float2 t00 = *(const float2*)(tl + 2u * i00);
        float2 t10 = *(const float2*)(tl + 2u * i10);
        float2 t01 = *(const float2*)(tl + 2u * i01);
        float2 t11 = *(const float2*)(tl + 2u * i11);

        float w00 = (1.0f - wx) * (1.0f - wy);
        float w10 = wx * (1.0f - wy);
        float w01 = (1.0f - wx) * wy;
        float w11 = wx * wy;

        float f0 = fmaf(w00, t00.x, fmaf(w10, t10.x, fmaf(w01, t01.x, w11 * t11.x)));
        float f1 = fmaf(w00, t00.y, fmaf(w10, t10.y, fmaf(w01, t01.y, w11 * t11.y)));

        const float* w1r0 = W1 + (2 * lvl) * 64;
        const float* w1r1 = W1 + (2 * lvl + 1) * 64;
#pragma unroll
        for (int j = 0; j < 64; j++)
            h1[j] = fmaf(f0, w1r0[j], fmaf(f1, w1r1[j], h1[j]));
    }

    // hashed levels 6..15 from precomputed fp16 feats (coalesced streams)
#pragma unroll
    for (int l = 0; l < N_HASHED; l++) {
        __half2 h = feats[(size_t)l * (size_t)n + i];
        float f0 = __low2float(h);
        float f1 = __high2float(h);
        const float* w1r0 = W1 + (2 * (l + LVL0_HASH)) * 64;
        const float* w1r1 = W1 + (2 * (l + LVL0_HASH) + 1) * 64;
#pragma unroll
        for (int j = 0; j < 64; j++)
            h1[j] = fmaf(f0, w1r0[j], fmaf(f1, w1r1[j], h1[j]));
    }

#pragma unroll
    for (int j = 0; j < 64; j++) h1[j] = fmaxf(h1[j], 0.0f);

    float h2[64];
#pragma unroll
    for (int j = 0; j < 64; j++) h2[j] = 0.0f;
#pragma unroll
    for (int k = 0; k < 64; k++) {
        float a = h1[k];
        const float* wr = W2 + k * 64;
#pragma unroll
        for (int j = 0; j < 64; j++)
            h2[j] = fmaf(a, wr[j], h2[j]);
    }
#pragma unroll
    for (int j = 0; j < 64; j++) h2[j] = fmaxf(h2[j], 0.0f);

    float o0 = 0.0f, o1 = 0.0f, o2 = 0.0f;
#pragma unroll
    for (int k = 0; k < 64; k++) {
        float a = h2[k];
        o0 = fmaf(a, W3[k * 3 + 0], o0);
        o1 = fmaf(a, W3[k * 3 + 1], o1);
        o2 = fmaf(a, W3[k * 3 + 2], o2);
    }

    out[3 * i + 0] = o0;
    out[3 * i + 1] = o1;
    out[3 * i + 2] = o2;
}

// ---------- Fallback: R1 monolithic kernel (used if ws too small) ----------
__global__ __launch_bounds__(256, 2)
void ngp_mono(const float* __restrict__ pos, const float* __restrict__ table,
              const float* __restrict__ W1, const float* __restrict__ W2,
              const float* __restrict__ W3, float* __restrict__ out, int n)
{
    int i = blockIdx.x * blockDim.x + threadIdx.x;
    if (i >= n) return;
    float px = pos[2 * i], py = pos[2 * i + 1];
    float h1[64];
#pragma unroll
    for (int j = 0; j < 64; j++) h1[j] = 0.0f;
#pragma unroll
    for (int lvl = 0; lvl < 16; lvl++) {
        const unsigned res = 16u << lvl;
        const float scale = (float)res - 1.0f;
        float pxs = fmaf(px, scale, 0.5f);
        float pys = fmaf(py, scale, 0.5f);
        float fx = floorf(pxs), fy = floorf(pys);
        float wx = pxs - fx, wy = pys - fy;
        unsigned x0 = (unsigned)fx, y0 = (unsigned)fy;
        unsigned i00, i10, i01, i11;
        if ((unsigned long long)res * (unsigned long long)res <= (unsigned long long)TSIZE) {
            i00 = x0 + y0 * res; i10 = i00 + 1u; i01 = i00 + res; i11 = i01 + 1u;
        } else {
            unsigned hy0 = y0 * PRIME2, hy1 = (y0 + 1u) * PRIME2;
            i00 = (x0 ^ hy0) & (TSIZE - 1u);
            i10 = ((x0 + 1u) ^ hy0) & (TSIZE - 1u);
            i01 = (x0 ^ hy1) & (TSIZE - 1u);
            i11 = ((x0 + 1u) ^ hy1) & (TSIZE - 1u);
        }
        const float* tl = table + (size_t)lvl * (size_t)TSIZE * 2u;
        float2 t00 = *(const float2*)(tl + 2u * i00);
        float2 t10 = *(const float2*)(tl + 2u * i10);
        float2 t01 = *(const float2*)(tl + 2u * i01);
        float2 t11 = *(const float2*)(tl + 2u * i11);
        float w00 = (1.0f - wx) * (1.0f - wy);
        float w10 = wx * (1.0f - wy);
        float w01 = (1.0f - wx) * wy;
        float w11 = wx * wy;
        float f0 = fmaf(w00, t00.x, fmaf(w10, t10.x, fmaf(w01, t01.x, w11 * t11.x)));
        float f1 = fmaf(w00, t00.y, fmaf(w10, t10.y, fmaf(w01, t01.y, w11 * t11.y)));
        const float* w1r0 = W1 + (2 * lvl) * 64;
        const float* w1r1 = W1 + (2 * lvl + 1) * 64;
#pragma unroll
        for (int j = 0; j < 64; j++)
            h1[j] = fmaf(f0, w1r0[j], fmaf(f1, w1r1[j], h1[j]));
    }
#pragma unroll
    for (int j = 0; j < 64; j++) h1[j] = fmaxf(h1[j], 0.0f);
    float h2[64];
#pragma unroll
    for (int j = 0; j < 64; j++) h2[j] = 0.0f;
#pragma unroll
    for (int k = 0; k < 64; k++) {
        float a = h1[k];
        const float* wr = W2 + k * 64;
#pragma unroll
        for (int j = 0; j < 64; j++) h2[j] = fmaf(a, wr[j], h2[j]);
    }
#pragma unroll
    for (int j = 0; j < 64; j++) h2[j] = fmaxf(h2[j], 0.0f);
    float o0 = 0.0f, o1 = 0.0f, o2 = 0.0f;
#pragma unroll
    for (int k = 0; k < 64; k++) {
        float a = h2[k];
        o0 = fmaf(a, W3[k * 3 + 0], o0);
        o1 = fmaf(a, W3[k * 3 + 1], o1);
        o2 = fmaf(a, W3[k * 3 + 2], o2);
    }
    out[3 * i + 0] = o0; out[3 * i + 1] = o1; out[3 * i + 2] = o2;
}

extern "C" void kernel_launch(void* const* d_in, const int* in_sizes, int n_in,
                              void* d_out, int out_size, void* d_ws, size_t ws_size,
                              hipStream_t stream) {
    const float* pos   = (const float*)d_in[0];
    const float* table = (const float*)d_in[1];
    const float* W1    = (const float*)d_in[2];
    const float* W2    = (const float*)d_in[3];
    const float* W3    = (const float*)d_in[4];
    float* out = (float*)d_out;

    int n = in_sizes[0] / 2;

    size_t tbl16_bytes = (size_t)N_HASHED * TSIZE * 4u;            // 20 MB
    size_t feats_bytes = (size_t)N_HASHED * (size_t)n * 4u;        // 168 MB
    size_t need = tbl16_bytes + feats_bytes;

    if (ws_size < need || (n & 511)) {
        int blocks = (n + 255) / 256;
        hipLaunchKernelGGL(ngp_mono, dim3(blocks), dim3(256), 0, stream,
                           pos, table, W1, W2, W3, out, n);
        return;
    }

    unsigned* tbl16 = (unsigned*)d_ws;
    __half2* feats  = (__half2*)((char*)d_ws + tbl16_bytes);

    // K0: fp32 -> fp16 table conversion for hashed levels
    {
        int n2 = (N_HASHED * TSIZE) / 2;   // 2 entries per thread
        int blocks = (n2 + 255) / 256;
        hipLaunchKernelGGL(cvt_table, dim3(blocks), dim3(256), 0, stream,
                           table + (size_t)LVL0_HASH * TSIZE * 2u, tbl16, n2);
    }

    // K1 x10: one hashed level at a time (keeps 2 MB table L2-resident per XCD)
    {
        int nhalf = n / 2;
        int blocks = (nhalf + 255) / 256;
        for (int l = 0; l < N_HASHED; l++) {
            const __half2* tbl_l = (const __half2*)(tbl16 + (size_t)l * TSIZE);
            uint2* feat_l = (uint2*)(feats + (size_t)l * (size_t)n);
            unsigned res = 16u << (l + LVL0_HASH);
            hipLaunchKernelGGL(encode_level, dim3(blocks), dim3(256), 0, stream,
                               pos, tbl_l, feat_l, nhalf, res);
        }
    }

    // K2: coarse levels + MLP
    {
        int blocks = (n + 255) / 256;
        hipLaunchKernelGGL(mlp_kernel, dim3(blocks), dim3(256), 0, stream,
                           pos, table, feats, W1, W2, W3, out, n);
    }
}

// Round 7
// 907.517 us; speedup vs baseline: 2.0794x; 1.5053x over previous
//
#include <hip/hip_runtime.h>
#include <hip/hip_fp16.h>

// NGP fwd: per-hashed-level encode (L2-resident fp16 table) + fp16-MFMA MLP.
// N = 4,194,304 points. Table: [16, 2^19, 2] fp32. Levels 0-5 dense, 6-15 hashed.
// fp16 activations carry a global scale S=4096 (bias-free MLP + ReLU => scale
// transparent; removed at final store).
// LDS transpose: ALL accesses volatile + barriers. The buffer is type-punned
// (u32 writes / f16x8 reads); without volatile, TBAA lets the compiler hoist
// or CSE a slice of ds_reads across ds_writes (R5/R6: one-of-64-features
// stale => 2-4e-5 structural error).

constexpr unsigned TSIZE  = 1u << 19;
constexpr unsigned PRIME2 = 2654435761u;
constexpr int N_HASHED    = 10;      // levels 6..15
constexpr int LVL0_HASH   = 6;
#define FEAT_SCALE   4096.0f
#define INV_SCALE    (1.0f / 4096.0f)

typedef _Float16 f16x8 __attribute__((ext_vector_type(8)));
typedef float    f32x4 __attribute__((ext_vector_type(4)));
typedef unsigned u32x2 __attribute__((ext_vector_type(2)));
typedef unsigned u32x4 __attribute__((ext_vector_type(4)));

__device__ __forceinline__ unsigned pkh2(float a, float b) {
    __half2 h = __floats2half2_rn(a, b);
    unsigned u; __builtin_memcpy(&u, &h, 4); return u;
}

// ---------- K0: hashed-level tables fp32 -> fp16*S (into ws) ----------
__global__ __launch_bounds__(256)
void cvt_table(const float* __restrict__ src, unsigned* __restrict__ dst, int n2)
{
    int t = blockIdx.x * blockDim.x + threadIdx.x;
    if (t >= n2) return;
    float4 v = ((const float4*)src)[t];
    uint2 pk;
    pk.x = pkh2(v.x * FEAT_SCALE, v.y * FEAT_SCALE);
    pk.y = pkh2(v.z * FEAT_SCALE, v.w * FEAT_SCALE);
    ((uint2*)dst)[t] = pk;
}

// ---------- K1: one hashed level -> fp16 feats (level-major, scaled) ----------
__device__ __forceinline__ void hash_feat(float px, float py, float scale,
                                          const __half2* __restrict__ tbl,
                                          unsigned& out_h2)
{
    float pxs = fmaf(px, scale, 0.5f);
    float pys = fmaf(py, scale, 0.5f);
    float fx = floorf(pxs), fy = floorf(pys);
    float wx = pxs - fx,   wy = pys - fy;
    unsigned x0 = (unsigned)fx, y0 = (unsigned)fy;

    unsigned hy0 = y0 * PRIME2;
    unsigned hy1 = (y0 + 1u) * PRIME2;
    unsigned i00 = (x0 ^ hy0) & (TSIZE - 1u);
    unsigned i10 = ((x0 + 1u) ^ hy0) & (TSIZE - 1u);
    unsigned i01 = (x0 ^ hy1) & (TSIZE - 1u);
    unsigned i11 = ((x0 + 1u) ^ hy1) & (TSIZE - 1u);

    __half2 t00 = tbl[i00];
    __half2 t10 = tbl[i10];
    __half2 t01 = tbl[i01];
    __half2 t11 = tbl[i11];

    float w00 = (1.0f - wx) * (1.0f - wy);
    float w10 = wx * (1.0f - wy);
    float w01 = (1.0f - wx) * wy;
    float w11 = wx * wy;

    float f0 = w00 * __low2float(t00)  + w10 * __low2float(t10)
             + w01 * __low2float(t01)  + w11 * __low2float(t11);
    float f1 = w00 * __high2float(t00) + w10 * __high2float(t10)
             + w01 * __high2float(t01) + w11 * __high2float(t11);

    out_h2 = pkh2(f0, f1);   // table already scaled by S
}

__global__ __launch_bounds__(256)
void encode_level(const float* __restrict__ pos,
                  const __half2* __restrict__ tbl,
                  uint2* __restrict__ feat,
                  int nhalf, unsigned res)
{
    int t = blockIdx.x * blockDim.x + threadIdx.x;
    if (t >= nhalf) return;
    float4 p = ((const float4*)pos)[t];
    float scale = (float)res - 1.0f;
    uint2 pk;
    hash_feat(p.x, p.y, scale, tbl, pk.x);
    hash_feat(p.z, p.w, scale, tbl, pk.y);
    feat[t] = pk;
}

// ---------- K2: coarse levels + fp16 MFMA MLP (transposed layers) ----------
// Per wave: 64 points. All layers as D^T = W^T * act^T:
//   A-frag = weight tile (once per wave), A[m=lane&15][k=q*8+j].
//   B-frag lane&15 = point, k = q*8+j.
//   C/D: col(lane&15)=point, row=(lane>>4)*4+reg = feature.
// One 9216 B wave-private buffer reused feats->h1->h2; volatile + barriers.
#define S0B 80    // act0 row stride bytes  (40 halfs)
#define S1B 144   // act1/2 row stride bytes (72 halfs)

__global__ __launch_bounds__(256)
void mlp_mfma(const float* __restrict__ pos,
              const float* __restrict__ table,
              const unsigned* __restrict__ feats,  // [10][N] half2 as uint, scaled
              const float* __restrict__ W1,        // [32,64]
              const float* __restrict__ W2,        // [64,64]
              const float* __restrict__ W3,        // [64,3]
              float* __restrict__ out, int n)
{
    __shared__ uint4 lds[4 * 9216 / 16];
    const int lane = threadIdx.x & 63;
    const int wid  = threadIdx.x >> 6;
    const int m    = lane & 15;      // point-within-tile (B/N index)
    const int q    = lane >> 4;      // quad
    char* buf = (char*)lds + wid * 9216;

    // ---- weight A-frags (once per wave) ----
    f16x8 A1[4];
#pragma unroll
    for (int ft = 0; ft < 4; ft++)
#pragma unroll
        for (int j = 0; j < 8; j++)
            A1[ft][j] = (_Float16)W1[(q * 8 + j) * 64 + ft * 16 + m];

    f16x8 A2[4][2];
#pragma unroll
    for (int ft = 0; ft < 4; ft++)
#pragma unroll
        for (int kb = 0; kb < 2; kb++)
#pragma unroll
            for (int j = 0; j < 8; j++)
                A2[ft][kb][j] = (_Float16)W2[(kb * 32 + q * 8 + j) * 64 + ft * 16 + m];

    f16x8 A3[2];
#pragma unroll
    for (int kb = 0; kb < 2; kb++)
#pragma unroll
        for (int j = 0; j < 8; j++)
            A3[kb][j] = (m < 3) ? (_Float16)W3[(kb * 32 + q * 8 + j) * 3 + m]
                                : (_Float16)0.f;

    const int ntiles  = n >> 6;
    const int wstride = gridDim.x * 4;
    const int niter   = (ntiles + wstride - 1) / wstride;   // uniform trip count

    for (int it = 0; it < niter; it++) {
        const int t = blockIdx.x * 4 + wid + it * wstride;
        const bool active = (t < ntiles);
        const int p0 = t << 6;
        const int p  = p0 + lane;

        // ---- P0: this lane's 32 features (fp16-packed, scaled) -> LDS ----
        if (active) {
            unsigned fl[16];
            float px = pos[2 * p], py = pos[2 * p + 1];
#pragma unroll
            for (int lvl = 0; lvl < 6; lvl++) {
                const unsigned res = 16u << lvl;
                const float scale = (float)res - 1.0f;
                float pxs = fmaf(px, scale, 0.5f);
                float pys = fmaf(py, scale, 0.5f);
                float fx = floorf(pxs), fy = floorf(pys);
                float wx = pxs - fx,   wy = pys - fy;
                unsigned x0 = (unsigned)fx, y0 = (unsigned)fy;
                unsigned i00 = x0 + y0 * res;
                const float* tl = table + (size_t)lvl * (size_t)TSIZE * 2u;
                float2 t00 = *(const float2*)(tl + 2u * i00);
                float2 t10 = *(const float2*)(tl + 2u * (i00 + 1u));
                float2 t01 = *(const float2*)(tl + 2u * (i00 + res));
                float2 t11 = *(const float2*)(tl + 2u * (i00 + res + 1u));
                float w00 = (1.0f - wx) * (1.0f - wy);
                float w10 = wx * (1.0f - wy);
                float w01 = (1.0f - wx) * wy;
                float w11 = wx * wy;
                float f0 = fmaf(w00, t00.x, fmaf(w10, t10.x, fmaf(w01, t01.x, w11 * t11.x)));
                float f1 = fmaf(w00, t00.y, fmaf(w10, t10.y, fmaf(w01, t01.y, w11 * t11.y)));
                fl[lvl] = pkh2(f0 * FEAT_SCALE, f1 * FEAT_SCALE);
            }
#pragma unroll
            for (int l = 0; l < N_HASHED; l++)
                fl[6 + l] = feats[(size_t)l * (size_t)n + p];

            volatile u32x4* w = (volatile u32x4*)(buf + lane * S0B);
            u32x4 w0 = {fl[0],  fl[1],  fl[2],  fl[3]};
            u32x4 w1 = {fl[4],  fl[5],  fl[6],  fl[7]};
            u32x4 w2 = {fl[8],  fl[9],  fl[10], fl[11]};
            u32x4 w3 = {fl[12], fl[13], fl[14], fl[15]};
            w[0] = w0; w[1] = w1; w[2] = w2; w[3] = w3;
        }
        __syncthreads();   // feats visible before B1 reads

        f16x8 B1[4];
        if (active) {
#pragma unroll
            for (int pt = 0; pt < 4; pt++)
                B1[pt] = *(volatile const f16x8*)(buf + (pt * 16 + m) * S0B + q * 16);
        }
        __syncthreads();   // all B1 reads done before h1 overwrites buffer

        if (active) {
#pragma unroll
            for (int ft = 0; ft < 4; ft++) {
#pragma unroll
                for (int pt = 0; pt < 4; pt++) {
                    f32x4 acc = {0.f, 0.f, 0.f, 0.f};
                    acc = __builtin_amdgcn_mfma_f32_16x16x32_f16(A1[ft], B1[pt], acc, 0, 0, 0);
                    u32x2 pk = {pkh2(fmaxf(acc[0], 0.f), fmaxf(acc[1], 0.f)),
                                pkh2(fmaxf(acc[2], 0.f), fmaxf(acc[3], 0.f))};
                    *(volatile u32x2*)(buf + (pt * 16 + m) * S1B + (ft * 16 + q * 4) * 2) = pk;
                }
            }
        }
        __syncthreads();   // h1 visible before B2 reads

        f16x8 B2[4][2];
        if (active) {
#pragma unroll
            for (int pt = 0; pt < 4; pt++)
#pragma unroll
                for (int kb = 0; kb < 2; kb++)
                    B2[pt][kb] = *(volatile const f16x8*)(buf + (pt * 16 + m) * S1B + kb * 64 + q * 16);
        }
        __syncthreads();   // all B2 reads done before h2 overwrites buffer

        if (active) {
#pragma unroll
            for (int ft = 0; ft < 4; ft++) {
#pragma unroll
                for (int pt = 0; pt < 4; pt++) {
                    f32x4 acc = {0.f, 0.f, 0.f, 0.f};
                    acc = __builtin_amdgcn_mfma_f32_16x16x32_f16(A2[ft][0], B2[pt][0], acc, 0, 0, 0);
                    acc = __builtin_amdgcn_mfma_f32_16x16x32_f16(A2[ft][1], B2[pt][1], acc, 0, 0, 0);
                    u32x2 pk = {pkh2(fmaxf(acc[0], 0.f), fmaxf(acc[1], 0.f)),
                                pkh2(fmaxf(acc[2], 0.f), fmaxf(acc[3], 0.f))};
                    *(volatile u32x2*)(buf + (pt * 16 + m) * S1B + (ft * 16 + q * 4) * 2) = pk;
                }
            }
        }
        __syncthreads();   // h2 visible before B3 reads

        if (active) {
            f16x8 B3[4][2];
#pragma unroll
            for (int pt = 0; pt < 4; pt++)
#pragma unroll
                for (int kb = 0; kb < 2; kb++)
                    B3[pt][kb] = *(volatile const f16x8*)(buf + (pt * 16 + m) * S1B + kb * 64 + q * 16);

#pragma unroll
            for (int pt = 0; pt < 4; pt++) {
                f32x4 acc = {0.f, 0.f, 0.f, 0.f};
                acc = __builtin_amdgcn_mfma_f32_16x16x32_f16(A3[0], B3[pt][0], acc, 0, 0, 0);
                acc = __builtin_amdgcn_mfma_f32_16x16x32_f16(A3[1], B3[pt][1], acc, 0, 0, 0);
                if (q == 0) {
                    int po = p0 + pt * 16 + m;
                    out[3 * po + 0] = acc[0] * INV_SCALE;
                    out[3 * po + 1] = acc[1] * INV_SCALE;
                    out[3 * po + 2] = acc[2] * INV_SCALE;
                }
            }
        }
        __syncthreads();   // B3 reads done before next tile's feat writes
    }
}

// ---------- Fallback: monolithic fp32 (used if ws too small / odd n) ----------
__global__ __launch_bounds__(256, 2)
void ngp_mono(const float* __restrict__ pos, const float* __restrict__ table,
              const float* __restrict__ W1, const float* __restrict__ W2,
              const float* __restrict__ W3, float* __restrict__ out, int n)
{
    int i = blockIdx.x * blockDim.x + threadIdx.x;
    if (i >= n) return;
    float px = pos[2 * i], py = pos[2 * i + 1];
    float h1[64];
#pragma unroll
    for (int j = 0; j < 64; j++) h1[j] = 0.0f;
#pragma unroll
    for (int lvl = 0; lvl < 16; lvl++) {
        const unsigned res = 16u << lvl;
        const float scale = (float)res - 1.0f;
        float pxs = fmaf(px, scale, 0.5f);
        float pys = fmaf(py, scale, 0.5f);
        float fx = floorf(pxs), fy = floorf(pys);
        float wx = pxs - fx, wy = pys - fy;
        unsigned x0 = (unsigned)fx, y0 = (unsigned)fy;
        unsigned i00, i10, i01, i11;
        if ((unsigned long long)res * (unsigned long long)res <= (unsigned long long)TSIZE) {
            i00 = x0 + y0 * res; i10 = i00 + 1u; i01 = i00 + res; i11 = i01 + 1u;
        } else {
            unsigned hy0 = y0 * PRIME2, hy1 = (y0 + 1u) * PRIME2;
            i00 = (x0 ^ hy0) & (TSIZE - 1u);
            i10 = ((x0 + 1u) ^ hy0) & (TSIZE - 1u);
            i01 = (x0 ^ hy1) & (TSIZE - 1u);
            i11 = ((x0 + 1u) ^ hy1) & (TSIZE - 1u);
        }
        const float* tl = table + (size_t)lvl * (size_t)TSIZE * 2u;
        float2 t00 = *(const float2*)(tl + 2u * i00);
        float2 t10 = *(const float2*)(tl + 2u * i10);
        float2 t01 = *(const float2*)(tl + 2u * i01);
        float2 t11 = *(const float2*)(tl + 2u * i11);
        float w00 = (1.0f - wx) * (1.0f - wy);
        float w10 = wx * (1.0f - wy);
        float w01 = (1.0f - wx) * wy;
        float w11 = wx * wy;
        float f0 = fmaf(w00, t00.x, fmaf(w10, t10.x, fmaf(w01, t01.x, w11 * t11.x)));
        float f1 = fmaf(w00, t00.y, fmaf(w10, t10.y, fmaf(w01, t01.y, w11 * t11.y)));
        const float* w1r0 = W1 + (2 * lvl) * 64;
        const float* w1r1 = W1 + (2 * lvl + 1) * 64;
#pragma unroll
        for (int j = 0; j < 64; j++)
            h1[j] = fmaf(f0, w1r0[j], fmaf(f1, w1r1[j], h1[j]));
    }
#pragma unroll
    for (int j = 0; j < 64; j++) h1[j] = fmaxf(h1[j], 0.0f);
    float h2[64];
#pragma unroll
    for (int j = 0; j < 64; j++) h2[j] = 0.0f;
#pragma unroll
    for (int k = 0; k < 64; k++) {
        float a = h1[k];
        const float* wr = W2 + k * 64;
#pragma unroll
        for (int j = 0; j < 64; j++) h2[j] = fmaf(a, wr[j], h2[j]);
    }
#pragma unroll
    for (int j = 0; j < 64; j++) h2[j] = fmaxf(h2[j], 0.0f);
    float o0 = 0.0f, o1 = 0.0f, o2 = 0.0f;
#pragma unroll
    for (int k = 0; k < 64; k++) {
        float a = h2[k];
        o0 = fmaf(a, W3[k * 3 + 0], o0);
        o1 = fmaf(a, W3[k * 3 + 1], o1);
        o2 = fmaf(a, W3[k * 3 + 2], o2);
    }
    out[3 * i + 0] = o0; out[3 * i + 1] = o1; out[3 * i + 2] = o2;
}

extern "C" void kernel_launch(void* const* d_in, const int* in_sizes, int n_in,
                              void* d_out, int out_size, void* d_ws, size_t ws_size,
                              hipStream_t stream) {
    const float* pos   = (const float*)d_in[0];
    const float* table = (const float*)d_in[1];
    const float* W1    = (const float*)d_in[2];
    const float* W2    = (const float*)d_in[3];
    const float* W3    = (const float*)d_in[4];
    float* out = (float*)d_out;

    int n = in_sizes[0] / 2;

    size_t tbl16_bytes = (size_t)N_HASHED * TSIZE * 4u;            // 20 MB
    size_t feats_bytes = (size_t)N_HASHED * (size_t)n * 4u;        // 168 MB
    size_t need = tbl16_bytes + feats_bytes;

    if (ws_size < need || (n & 511)) {
        int blocks = (n + 255) / 256;
        hipLaunchKernelGGL(ngp_mono, dim3(blocks), dim3(256), 0, stream,
                           pos, table, W1, W2, W3, out, n);
        return;
    }

    unsigned* tbl16 = (unsigned*)d_ws;
    __half2* feats  = (__half2*)((char*)d_ws + tbl16_bytes);

    // K0: fp32 -> fp16*S table conversion for hashed levels
    {
        int n2 = (N_HASHED * TSIZE) / 2;
        int blocks = (n2 + 255) / 256;
        hipLaunchKernelGGL(cvt_table, dim3(blocks), dim3(256), 0, stream,
                           table + (size_t)LVL0_HASH * TSIZE * 2u, tbl16, n2);
    }

    // K1 x10: one hashed level at a time (keeps 2 MB table L2-resident)
    {
        int nhalf = n / 2;
        int blocks = (nhalf + 255) / 256;
        for (int l = 0; l < N_HASHED; l++) {
            const __half2* tbl_l = (const __half2*)(tbl16 + (size_t)l * TSIZE);
            uint2* feat_l = (uint2*)(feats + (size_t)l * (size_t)n);
            unsigned res = 16u << (l + LVL0_HASH);
            hipLaunchKernelGGL(encode_level, dim3(blocks), dim3(256), 0, stream,
                               pos, tbl_l, feat_l, nhalf, res);
        }
    }

    // K2: coarse levels + fp16 MFMA MLP
    {
        hipLaunchKernelGGL(mlp_mfma, dim3(1024), dim3(256), 0, stream,
                           pos, table, (const unsigned*)feats, W1, W2, W3, out, n);
    }
}